// Round 3
// baseline (348.035 us; speedup 1.0000x reference)
//
#include <hip/hip_runtime.h>
#include <math.h>

// Problem constants
#define BB 16
#define CC 128
#define NN 16384          // 128*128 spatial tokens
#define NHEADS 8
#define HD 16             // head dim
#define SCALE 0.08838834764831843f   // 1/sqrt(128)

typedef __attribute__((ext_vector_type(8))) short short8;
typedef __attribute__((ext_vector_type(4))) unsigned short ushort4v;
typedef __attribute__((ext_vector_type(16))) float f32x16;

// Truncation bf16 split: hi = trunc16(v), lo = trunc16(v - hi)  (v-hi exact in fp32)
#define CVT(comp, hh, ll)                                                    \
    {                                                                        \
        unsigned int u = __float_as_uint(comp);                              \
        hh = (unsigned short)(u >> 16);                                      \
        float lf = (comp) - __uint_as_float(u & 0xffff0000u);                \
        ll = (unsigned short)(__float_as_uint(lf) >> 16);                    \
    }

// ---------------------------------------------------------------------------
// k1: per-batch partial Gram via split-bf16 MFMA (3-term: hh+hl+lh).
// grid (CH, 16 b), 512 threads = 8 waves. Full 16-tile (4x4 of 32x32) Gram;
// wave w owns tiles (bi=w>>1, bj=2*(w&1)) and (bi, bj+1) over ALL K of each
// 64-token stage -> acc = 2 x f32x16 = 32 VGPR, no cross-wave reduce.
// LDS [ch][64 tok] bf16 hi/lo planes, XOR-swizzled (ushort idx ^= (ch&7)<<3).
// ---------------------------------------------------------------------------
__global__ __launch_bounds__(512, 4) void k1_gram(const float* __restrict__ x,
                                                  float* __restrict__ pG,
                                                  float* __restrict__ pS,
                                                  int CH) {
    const int chunk = blockIdx.x;
    const int b = blockIdx.y;
    const int tid = threadIdx.x;
    const int w = tid >> 6;          // wave 0..7
    const int l = tid & 63;
    const int lr = l & 31, lh = l >> 5;
    const int ch0 = tid >> 4;        // staging: channel base 0..31
    const int t4 = tid & 15;         // staging: float4 index within 64-token stage
    const int NCB = NN / CH;
    const int NSTAGE = NCB >> 6;

    __shared__ __align__(16) unsigned short lds[2][2][128 * 64];  // [buf][hi/lo][ch*64+tok]

    const float* xg = x + (size_t)b * CC * NN + (size_t)chunk * NCB;

    const int bi = w >> 1;
    const int bj0 = (w & 1) * 2;

    f32x16 a0, a1;
#pragma unroll
    for (int r = 0; r < 16; ++r) { a0[r] = 0.0f; a1[r] = 0.0f; }

    float csum[4] = {0.0f, 0.0f, 0.0f, 0.0f};
    float4 ld[4];

    auto LOAD = [&](int s) {
#pragma unroll
        for (int k = 0; k < 4; ++k)
            ld[k] = *(const float4*)(xg + (size_t)(ch0 + 32 * k) * NN + s * 64 + t4 * 4);
    };

    auto CVW = [&](int buf) {
#pragma unroll
        for (int k = 0; k < 4; ++k) {
            float4 v = ld[k];
            csum[k] += v.x + v.y + v.z + v.w;
            const int ch = ch0 + 32 * k;
            const int idx = ((ch << 6) + (t4 << 2)) ^ ((ch & 7) << 3);
            unsigned short h0, h1, h2, h3, l0, l1, l2, l3;
            CVT(v.x, h0, l0)
            CVT(v.y, h1, l1)
            CVT(v.z, h2, l2)
            CVT(v.w, h3, l3)
            ushort4v hv = {h0, h1, h2, h3};
            ushort4v lv = {l0, l1, l2, l3};
            *(ushort4v*)&lds[buf][0][idx] = hv;
            *(ushort4v*)&lds[buf][1][idx] = lv;
        }
    };

    LOAD(0);
    CVW(0);
    __syncthreads();

    const int chA = bi * 32 + lr;
    const int chB0 = bj0 * 32 + lr;
    const int chB1 = chB0 + 32;
    const int swz = (lr & 7) << 3;

    for (int s = 0; s < NSTAGE; ++s) {
        const int bsel = s & 1;
        if (s + 1 < NSTAGE) LOAD(s + 1);     // prefetch under compute

#pragma unroll
        for (int ks = 0; ks < 4; ++ks) {
            const int tok = ks * 16 + 8 * lh;
            const int idxA = ((chA << 6) + tok) ^ swz;
            const int idxB0 = ((chB0 << 6) + tok) ^ swz;
            const int idxB1 = ((chB1 << 6) + tok) ^ swz;
            short8 ah = *(const short8*)&lds[bsel][0][idxA];
            short8 al = *(const short8*)&lds[bsel][1][idxA];
            short8 b0h = *(const short8*)&lds[bsel][0][idxB0];
            short8 b0l = *(const short8*)&lds[bsel][1][idxB0];
            short8 b1h = *(const short8*)&lds[bsel][0][idxB1];
            short8 b1l = *(const short8*)&lds[bsel][1][idxB1];
            a0 = __builtin_amdgcn_mfma_f32_32x32x16_bf16(ah, b0h, a0, 0, 0, 0);
            a0 = __builtin_amdgcn_mfma_f32_32x32x16_bf16(ah, b0l, a0, 0, 0, 0);
            a0 = __builtin_amdgcn_mfma_f32_32x32x16_bf16(al, b0h, a0, 0, 0, 0);
            a1 = __builtin_amdgcn_mfma_f32_32x32x16_bf16(ah, b1h, a1, 0, 0, 0);
            a1 = __builtin_amdgcn_mfma_f32_32x32x16_bf16(ah, b1l, a1, 0, 0, 0);
            a1 = __builtin_amdgcn_mfma_f32_32x32x16_bf16(al, b1h, a1, 0, 0, 0);
        }

        if (s + 1 < NSTAGE) CVW((s + 1) & 1);
        __syncthreads();
    }

    // ---- channel sums -> pS (reuse LDS as float scratch) ----
    float* scr = (float*)&lds[0][0][0];
#pragma unroll
    for (int k = 0; k < 4; ++k) scr[(ch0 + 32 * k) * 16 + t4] = csum[k];
    __syncthreads();
    if (tid < 128) {
        float s2 = 0.0f;
#pragma unroll
        for (int i = 0; i < 16; ++i) s2 += scr[tid * 16 + i];
        pS[(size_t)(b * CH + chunk) * 128 + tid] = s2;
    }

    // ---- each wave writes its 2 tiles (no cross-wave reduce) ----
    float* outp = pG + (size_t)(b * CH + chunk) * 16384;
#pragma unroll
    for (int r = 0; r < 16; ++r) {
        outp[(2 * w) * 1024 + r * 64 + l] = a0[r];
        outp[(2 * w + 1) * 1024 + r * 64 + l] = a1[r];
    }
}

// ---------------------------------------------------------------------------
// k1r: reduce partial Grams -> G (16 tiles, direct map), pS -> sB.
// MFMA C/D layout: col = lane&31, row = (reg&3) + 8*(reg>>2) + 4*(lane>>5).
// ---------------------------------------------------------------------------
__global__ __launch_bounds__(256) void k1_reduce(const float* __restrict__ pG,
                                                 const float* __restrict__ pS,
                                                 float* __restrict__ G,
                                                 float* __restrict__ sB,
                                                 int CH) {
    const int sg = blockIdx.x;
    const int b = blockIdx.y;
    const int tid = threadIdx.x;

    if (sg < 64) {
        const int e = sg * 256 + tid;       // 0..16383
        const int t = e >> 10;              // tile id
        const int rl = e & 1023;
        float sum = 0.0f;
        const float* p = pG + (size_t)b * CH * 16384 + e;
        for (int ch = 0; ch < CH; ++ch) sum += p[(size_t)ch * 16384];

        const int bi = t >> 2, bj = t & 3;
        const int reg = rl >> 6, lane = rl & 63;
        const int col = bj * 32 + (lane & 31);
        const int row = bi * 32 + (reg & 3) + 8 * (reg >> 2) + 4 * (lane >> 5);
        G[((size_t)b << 14) + row * CC + col] = sum;
    } else {
        if (tid < 128) {
            float s2 = 0.0f;
            for (int ch = 0; ch < CH; ++ch) s2 += pS[(size_t)(b * CH + ch) * 128 + tid];
            sB[b * CC + tid] = s2;
        }
    }
}

// ---------------------------------------------------------------------------
// k2a: per (b,h) scores + softmax. grid (8 h, 16 b), 256 threads.
// G(b) staged to LDS via float4 up-front (kills serial global-load chain).
// scores = (Wq G Wk^T + (Wq s) bk^T + bq (Wk s)^T + N bq bk^T) * SCALE
// ---------------------------------------------------------------------------
__global__ __launch_bounds__(256) void k2a_attn(const float* __restrict__ G,
                                                const float* __restrict__ sB,
                                                const float* __restrict__ w_qkv,
                                                const float* __restrict__ b_qkv,
                                                float* __restrict__ attn,
                                                float* __restrict__ cpre) {
    const int h = blockIdx.x;
    const int b = blockIdx.y;
    const int tid = threadIdx.x;

    __shared__ float Gs[CC * CC];    // 64 KiB
    __shared__ float wq_s[HD][132], wk_s[HD][132], Tq[HD][132];
    __shared__ float qs[HD], ks[HD], bqv[HD], bkv[HD], bvv[HD];
    __shared__ float sc[HD][HD + 1];

    {
        const float4* Gv = (const float4*)(G + ((size_t)b << 14));
        float4* Gsv = (float4*)Gs;
#pragma unroll
        for (int i = 0; i < 16; ++i) Gsv[tid + 256 * i] = Gv[tid + 256 * i];
    }
    for (int idx = tid; idx < HD * CC; idx += 256) {
        int r = idx >> 7, c = idx & 127;
        wq_s[r][c] = w_qkv[(h * HD + r) * CC + c];
        wk_s[r][c] = w_qkv[(CC + h * HD + r) * CC + c];
    }
    if (tid < HD) {
        bqv[tid] = b_qkv[h * HD + tid];
        bkv[tid] = b_qkv[CC + h * HD + tid];
        bvv[tid] = b_qkv[2 * CC + h * HD + tid];
    }
    __syncthreads();

    if (tid < 32) {
        int i = tid & 15;
        bool isK = tid >= 16;
        float sum = 0.0f;
        for (int c = 0; c < CC; ++c)
            sum += (isK ? wk_s[i][c] : wq_s[i][c]) * sB[b * CC + c];
        if (isK) ks[i] = sum; else qs[i] = sum;
    }

    {
        const int c2 = tid & 127;
        const int dh = tid >> 7;
        float t[8];
#pragma unroll
        for (int j = 0; j < 8; ++j) t[j] = 0.0f;
        for (int c1 = 0; c1 < CC; ++c1) {
            float g = Gs[c1 * CC + c2];
#pragma unroll
            for (int j = 0; j < 8; ++j) t[j] += wq_s[dh * 8 + j][c1] * g;
        }
        __syncthreads();
#pragma unroll
        for (int j = 0; j < 8; ++j) Tq[dh * 8 + j][c2] = t[j];
    }
    __syncthreads();

    {
        const int dd = tid >> 4, e = tid & 15;
        float sum = 0.0f;
        for (int c2 = 0; c2 < CC; ++c2) sum += Tq[dd][c2] * wk_s[e][c2];
        sum += qs[dd] * bkv[e] + bqv[dd] * ks[e] + (float)NN * bqv[dd] * bkv[e];
        sc[dd][e] = sum * SCALE;
    }
    __syncthreads();

    if (tid < HD) {
        const int dd = tid;
        float mx = -1e30f;
#pragma unroll
        for (int e = 0; e < HD; ++e) mx = fmaxf(mx, sc[dd][e]);
        float ex[HD];
        float den = 0.0f;
#pragma unroll
        for (int e = 0; e < HD; ++e) { ex[e] = __expf(sc[dd][e] - mx); den += ex[e]; }
        float inv = 1.0f / den;
        float cp = 0.0f;
#pragma unroll
        for (int e = 0; e < HD; ++e) {
            float a = ex[e] * inv;
            attn[((size_t)b * NHEADS + h) * HD * HD + dd * HD + e] = a;
            cp += a * bvv[e];
        }
        cpre[b * CC + h * HD + dd] = cp;
    }
}

// ---------------------------------------------------------------------------
// k2b: M = W_out * blockdiag(attn) * W_v, emitted as bf16 hi/lo planes
// Mh/Ml[b][o][c]. Per-head W_v staged to LDS. cvec = W_out cpre + b_out.
// grid (4 ogroups, 16 b), 256 threads.
// ---------------------------------------------------------------------------
__global__ __launch_bounds__(256) void k2b_M(const float* __restrict__ attn,
                                             const float* __restrict__ cpre,
                                             const float* __restrict__ w_qkv,
                                             const float* __restrict__ w_out,
                                             const float* __restrict__ b_out,
                                             unsigned short* __restrict__ Mh,
                                             unsigned short* __restrict__ Ml,
                                             float* __restrict__ cvec) {
    const int og = blockIdx.x;
    const int b = blockIdx.y;
    const int tid = threadIdx.x;

    __shared__ float Ph[HD][132];
    __shared__ float Vs[HD][132];
    __shared__ float wo_s[32][129];
    __shared__ float attn_s[CC][HD];
    __shared__ float cpre_s[CC];

    for (int idx = tid; idx < CC * HD; idx += 256)
        attn_s[idx >> 4][idx & 15] = attn[(size_t)b * CC * HD + idx];
    for (int idx = tid; idx < 32 * CC; idx += 256)
        wo_s[idx >> 7][idx & 127] = w_out[(og * 32 + (idx >> 7)) * CC + (idx & 127)];
    if (tid < CC) cpre_s[tid] = cpre[b * CC + tid];
    __syncthreads();

    const int c = tid & 127;
    const int oh = tid >> 7;
    float m[16];
#pragma unroll
    for (int j = 0; j < 16; ++j) m[j] = 0.0f;

    for (int hh = 0; hh < NHEADS; ++hh) {
        for (int idx = tid; idx < HD * CC; idx += 256)
            Vs[idx >> 7][idx & 127] = w_qkv[(2 * CC + hh * HD + (idx >> 7)) * CC + (idx & 127)];
        __syncthreads();
        for (int idx = tid; idx < HD * CC; idx += 256) {
            int dd = idx >> 7, cc = idx & 127;
            float s = 0.0f;
#pragma unroll
            for (int e = 0; e < HD; ++e)
                s += attn_s[hh * HD + dd][e] * Vs[e][cc];
            Ph[dd][cc] = s;
        }
        __syncthreads();
#pragma unroll
        for (int dd = 0; dd < HD; ++dd) {
            float p = Ph[dd][c];
#pragma unroll
            for (int j = 0; j < 16; ++j)
                m[j] += wo_s[oh * 16 + j][hh * HD + dd] * p;
        }
        __syncthreads();
    }

#pragma unroll
    for (int j = 0; j < 16; ++j) {
        const int o = og * 32 + oh * 16 + j;
        unsigned short hh2, ll2;
        CVT(m[j], hh2, ll2)
        Mh[((size_t)b << 14) + o * CC + c] = hh2;
        Ml[((size_t)b << 14) + o * CC + c] = ll2;
    }

    if (tid < 32) {
        float s = 0.0f;
        for (int r = 0; r < CC; ++r) s += wo_s[tid][r] * cpre_s[r];
        cvec[b * CC + og * 32 + tid] = s + b_out[og * 32 + tid];
    }
}

// ---------------------------------------------------------------------------
// k3: y = M x + c via split-bf16 MFMA (3-term). grid (64 chunks, 16 b),
// 256 threads = 4 waves. Block: 128 o x 256 tokens in four 64-token stages,
// double-buffered LDS x^T planes [n][c] (ushort idx c ^= (n&7)<<3 swizzle).
// Per-stage accumulators written out immediately -> acc stays 32 VGPR.
// M hi/lo fragments register-resident across all stages.
// ---------------------------------------------------------------------------
__global__ __launch_bounds__(256, 4) void k3_out(const float* __restrict__ x,
                                                 const unsigned short* __restrict__ Mh,
                                                 const unsigned short* __restrict__ Ml,
                                                 const float* __restrict__ cvec,
                                                 float* __restrict__ y) {
    const int chunk = blockIdx.x;    // 256 tokens each
    const int b = blockIdx.y;
    const int tid = threadIdx.x;
    const int w = tid >> 6;
    const int lane = tid & 63;

    __shared__ __align__(16) unsigned short xs[2][2][64 * 128];  // [buf][hi/lo][n*128+c]

    const float* xb = x + (size_t)b * CC * NN + (size_t)chunk * 256;

    // ---- preload M fragments for this wave's 32 output rows ----
    short8 Ah[8], Al[8];
    {
        const size_t mbase = ((size_t)b << 14) + (size_t)(32 * w + (lane & 31)) * CC;
#pragma unroll
        for (int ks = 0; ks < 8; ++ks) {
            const size_t off = mbase + 16 * ks + 8 * (lane >> 5);
            Ah[ks] = *(const short8*)&Mh[off];
            Al[ks] = *(const short8*)&Ml[off];
        }
    }

    float cvv[16];
#pragma unroll
    for (int r = 0; r < 16; ++r)
        cvv[r] = cvec[b * CC + 32 * w + (r & 3) + 8 * (r >> 2) + 4 * (lane >> 5)];

    float ldv[4][4];

    auto LOADH = [&](int s, int hf) {
#pragma unroll
        for (int k = 0; k < 4; ++k) {
            const int c0 = w * 4 + (4 * hf + k) * 16;
#pragma unroll
            for (int i = 0; i < 4; ++i)
                ldv[k][i] = xb[(size_t)(c0 + i) * NN + s * 64 + lane];
        }
    };

    auto CVWH = [&](int buf, int hf) {
#pragma unroll
        for (int k = 0; k < 4; ++k) {
            const int c0 = w * 4 + (4 * hf + k) * 16;
            const int idx = lane * 128 + (c0 ^ ((lane & 7) << 3));
            ushort4v hv, lv;
#pragma unroll
            for (int i = 0; i < 4; ++i) {
                unsigned short hh, ll;
                CVT(ldv[k][i], hh, ll)
                hv[i] = hh;
                lv[i] = ll;
            }
            *(ushort4v*)&xs[buf][0][idx] = hv;
            *(ushort4v*)&xs[buf][1][idx] = lv;
        }
    };

    LOADH(0, 0); CVWH(0, 0);
    LOADH(0, 1); CVWH(0, 1);
    __syncthreads();

    float* yb = y + (size_t)b * CC * NN + (size_t)chunk * 256;
    const int nl0 = lane & 31;
    const int cx0 = (nl0 & 7) << 3;
    const int nl1 = 32 + nl0;

    for (int s = 0; s < 4; ++s) {
        const int bsel = s & 1;
        f32x16 a0, a1;
#pragma unroll
        for (int r = 0; r < 16; ++r) { a0[r] = 0.0f; a1[r] = 0.0f; }

        if (s < 3) LOADH(s + 1, 0);

        // n-tile 0
#pragma unroll
        for (int ks = 0; ks < 8; ++ks) {
            const int idx = nl0 * 128 + ((16 * ks + 8 * (lane >> 5)) ^ cx0);
            short8 bh = *(const short8*)&xs[bsel][0][idx];
            short8 bl = *(const short8*)&xs[bsel][1][idx];
            a0 = __builtin_amdgcn_mfma_f32_32x32x16_bf16(Ah[ks], bh, a0, 0, 0, 0);
            a0 = __builtin_amdgcn_mfma_f32_32x32x16_bf16(Ah[ks], bl, a0, 0, 0, 0);
            a0 = __builtin_amdgcn_mfma_f32_32x32x16_bf16(Al[ks], bh, a0, 0, 0, 0);
        }

        if (s < 3) { CVWH(bsel ^ 1, 0); LOADH(s + 1, 1); }

        // n-tile 1
#pragma unroll
        for (int ks = 0; ks < 8; ++ks) {
            const int idx = nl1 * 128 + ((16 * ks + 8 * (lane >> 5)) ^ cx0);
            short8 bh = *(const short8*)&xs[bsel][0][idx];
            short8 bl = *(const short8*)&xs[bsel][1][idx];
            a1 = __builtin_amdgcn_mfma_f32_32x32x16_bf16(Ah[ks], bh, a1, 0, 0, 0);
            a1 = __builtin_amdgcn_mfma_f32_32x32x16_bf16(Ah[ks], bl, a1, 0, 0, 0);
            a1 = __builtin_amdgcn_mfma_f32_32x32x16_bf16(Al[ks], bh, a1, 0, 0, 0);
        }

        if (s < 3) CVWH(bsel ^ 1, 1);

        // ---- write this stage's 64 tokens ----
#pragma unroll
        for (int r = 0; r < 16; ++r) {
            const int o = 32 * w + (r & 3) + 8 * (r >> 2) + 4 * (lane >> 5);
            yb[(size_t)o * NN + s * 64 + nl0] = a0[r] + cvv[r];
            yb[(size_t)o * NN + s * 64 + nl1] = a1[r] + cvv[r];
        }
        __syncthreads();
    }
}

// ---------------------------------------------------------------------------
extern "C" void kernel_launch(void* const* d_in, const int* in_sizes, int n_in,
                              void* d_out, int out_size, void* d_ws, size_t ws_size,
                              hipStream_t stream) {
    const float* x     = (const float*)d_in[0];
    const float* w_qkv = (const float*)d_in[1];
    const float* b_qkv = (const float*)d_in[2];
    const float* w_out = (const float*)d_in[3];
    const float* b_out = (const float*)d_in[4];
    float* y = (float*)d_out;

    const size_t szG = (size_t)BB * CC * CC;
    const size_t szS = (size_t)BB * CC;
    const size_t szAttn = (size_t)BB * NHEADS * HD * HD;
    const size_t tail = szG + szS + szAttn + szS + szG + szS;

    int CH = 32;
    while (CH > 1 &&
           ((size_t)CH * BB * 16384 + (size_t)CH * BB * CC + tail) * sizeof(float) > ws_size)
        CH >>= 1;

    float* pG   = (float*)d_ws;
    float* pS   = pG + (size_t)CH * BB * 16384;   // 16 tiles * 1024 per (b,chunk)
    float* G    = pS + (size_t)CH * BB * CC;
    float* sB   = G + szG;
    float* attn = sB + szS;
    float* cpre = attn + szAttn;
    float* Mslab = cpre + szS;                    // szG floats = Mh + Ml ushort planes
    float* cvec = Mslab + szG;

    unsigned short* Mh = (unsigned short*)Mslab;
    unsigned short* Ml = Mh + (size_t)BB * CC * CC;

    k1_gram<<<dim3(CH, BB), 512, 0, stream>>>(x, pG, pS, CH);
    k1_reduce<<<dim3(65, BB), 256, 0, stream>>>(pG, pS, G, sB, CH);
    k2a_attn<<<dim3(NHEADS, BB), 256, 0, stream>>>(G, sB, w_qkv, b_qkv, attn, cpre);
    k2b_M<<<dim3(4, BB), 256, 0, stream>>>(attn, cpre, w_qkv, w_out, b_out, Mh, Ml, cvec);
    k3_out<<<dim3(64, BB), 256, 0, stream>>>(x, Mh, Ml, cvec, y);
}